// Round 4
// baseline (188.306 us; speedup 1.0000x reference)
//
#include <hip/hip_runtime.h>

typedef _Float16 f16x8 __attribute__((ext_vector_type(8)));
typedef _Float16 f16x4 __attribute__((ext_vector_type(4)));
typedef float f32x4 __attribute__((ext_vector_type(4)));

__device__ __forceinline__ void gload16(const void* g, void* l) {
  __builtin_amdgcn_global_load_lds(
      (__attribute__((address_space(1))) void*)g,
      (__attribute__((address_space(3))) void*)l, 16, 0, 0);
}

// W is scaled by 2^12 when cast to f16 (raw ~1e-5 values are f16-subnormal;
// denormal flush would delete the r@W term). Epilogue multiplies by 2^-12.
#define W_SCALE 4096.0f
#define W_UNSCALE (1.0f / 4096.0f)

// 16B-granular XOR swizzle within each 32-elem k-chunk, keyed by row&3.
// Applied to the GLOBAL image of gemm1's staged operands (global_load_lds
// writes LDS linearly), and inverted at fragment-read time.
#define SWZA(k, row) (((k) & ~31) | (((k) & 31) ^ (((row) & 3) << 3)))

// ---------------- conv 3x3 (1->16) + bias + relu + maxpool2 -> conv_flat f16 ----------------
// one thread per (b, pooled pixel); 16 channels per thread.
// Output is pre-swizzled (SWZA keyed by b) for gemm1's LDS staging.
__global__ __launch_bounds__(256) void conv_pool_kernel(
    const float* __restrict__ x,      // [8192][28][28]
    const float* __restrict__ cw,     // [16][9]
    const float* __restrict__ cb,     // [16]
    _Float16* __restrict__ out) {     // [8192][3136]  logical (c*196 + p), swizzled
  __shared__ float wsm[144];
  __shared__ float bsm[16];
  int tid = threadIdx.x;
  if (tid < 144) wsm[tid] = cw[tid];
  if (tid < 16) bsm[tid] = cb[tid];
  __syncthreads();
  if (tid >= 196) return;
  int b = blockIdx.x;
  int ph = tid / 14, pw = tid - ph * 14;
  const float* xb = x + b * 784;
  float xv[4][4];
  int r0 = 2 * ph - 1, c0 = 2 * pw - 1;
#pragma unroll
  for (int i = 0; i < 4; ++i) {
    int r = r0 + i;
#pragma unroll
    for (int j = 0; j < 4; ++j) {
      int c = c0 + j;
      xv[i][j] = (r >= 0 && r < 28 && c >= 0 && c < 28) ? xb[r * 28 + c] : 0.f;
    }
  }
#pragma unroll
  for (int ch = 0; ch < 16; ++ch) {
    float a0 = bsm[ch], a1 = a0, a2 = a0, a3 = a0;
#pragma unroll
    for (int i = 0; i < 3; ++i)
#pragma unroll
      for (int j = 0; j < 3; ++j) {
        float wv = wsm[ch * 9 + i * 3 + j];
        a0 = fmaf(wv, xv[i][j],     a0);
        a1 = fmaf(wv, xv[i][j + 1], a1);
        a2 = fmaf(wv, xv[i + 1][j],     a2);
        a3 = fmaf(wv, xv[i + 1][j + 1], a3);
      }
    float m = fmaxf(fmaxf(a0, a1), fmaxf(a2, a3));
    m = fmaxf(m, 0.f);
    int k = ch * 196 + tid;
    out[b * 3136 + SWZA(k, b)] = (_Float16)m;
  }
}

// ---------------- W_in fp32 -> fp16, pre-swizzled ----------------
// one block per n-row (256 blocks)
__global__ __launch_bounds__(256) void win_cvt_kernel(
    const float* __restrict__ in,     // [256][3136]
    _Float16* __restrict__ out) {     // [256][3136] swizzled
  int n = blockIdx.x, tid = threadIdx.x;
  const float* src = in + (size_t)n * 3136;
  _Float16* dst = out + (size_t)n * 3136;
#pragma unroll
  for (int it = 0; it < 4; ++it) {
    int idx = it * 256 + tid;          // float4 index, 784 per row
    if (idx < 784) {
      int k0 = idx * 4;
      float4 v = *(const float4*)(src + k0);
      f16x4 h = {(_Float16)v.x, (_Float16)v.y, (_Float16)v.z, (_Float16)v.w};
      *(f16x4*)(dst + SWZA(k0, n)) = h;   // 4-elem group stays contiguous under XOR>=bit3
    }
  }
}

// W [256][256] (k-major) -> Wt f16 [n][k] (n-major, plain), scaled by 2^12
__global__ void wt_cvt_kernel(const float* __restrict__ W,
                              _Float16* __restrict__ Wt) {
  int i = blockIdx.x * 256 + threadIdx.x;  // 65536
  int k = i >> 8, n = i & 255;             // coalesced read of W row k
  Wt[n * 256 + k] = (_Float16)(W[k * 256 + n] * W_SCALE);
}

// ---------------- GEMM1: [8192x3136] @ [3136x256] (+bias, relu) ----------------
// tile 64(M) x 128(N), BK=32; 4 waves, each 32x64 (2x4 frags of 16x16x32)
__global__ __launch_bounds__(256) void gemm1_kernel(
    const _Float16* __restrict__ A,   // [8192][3136] swizzled
    const _Float16* __restrict__ Bw,  // [256][3136]  swizzled (W_in, n-major)
    const float* __restrict__ bias,   // [256]
    float* __restrict__ Rf,           // [8192][256]
    _Float16* __restrict__ Rb) {      // [8192][256]
  const int K = 3136;
  __shared__ __align__(16) _Float16 As[64 * 32];
  __shared__ __align__(16) _Float16 Bs[128 * 32];
  int tid = threadIdx.x, lane = tid & 63, wid = tid >> 6;
  int bm = blockIdx.x * 64, bn = blockIdx.y * 128;
  f32x4 zero = {0.f, 0.f, 0.f, 0.f};
  f32x4 acc[2][4];
#pragma unroll
  for (int i = 0; i < 2; ++i)
#pragma unroll
    for (int j = 0; j < 4; ++j) acc[i][j] = zero;

  const _Float16* Ag  = A  + (size_t)(bm + wid * 16 + (lane >> 2)) * K + (lane & 3) * 8;
  const _Float16* Bg0 = Bw + (size_t)(bn + wid * 32 + (lane >> 2)) * K + (lane & 3) * 8;
  const _Float16* Bg1 = Bg0 + 16 * K;
  _Float16* Asw  = As + wid * 512;   // wave-uniform LDS dest (lane*16B implicit)
  _Float16* Bsw0 = Bs + wid * 1024;
  _Float16* Bsw1 = Bsw0 + 512;

  int wm = (wid & 1) * 32, wn = (wid >> 1) * 64;
  int koff = (lane >> 4) * 8;
  for (int k0 = 0; k0 < K; k0 += 32) {
    __syncthreads();
    gload16(Ag + k0, Asw);
    gload16(Bg0 + k0, Bsw0);
    gload16(Bg1 + k0, Bsw1);
    __syncthreads();
    f16x8 af[2];
#pragma unroll
    for (int mi = 0; mi < 2; ++mi) {
      int ar = wm + mi * 16 + (lane & 15);
      af[mi] = *(const f16x8*)(As + ar * 32 + (koff ^ ((ar & 3) << 3)));
    }
#pragma unroll
    for (int ni = 0; ni < 4; ++ni) {
      int br = wn + ni * 16 + (lane & 15);
      f16x8 bf = *(const f16x8*)(Bs + br * 32 + (koff ^ ((br & 3) << 3)));
      acc[0][ni] = __builtin_amdgcn_mfma_f32_16x16x32_f16(af[0], bf, acc[0][ni], 0, 0, 0);
      acc[1][ni] = __builtin_amdgcn_mfma_f32_16x16x32_f16(af[1], bf, acc[1][ni], 0, 0, 0);
    }
  }
  int rg = (lane >> 4) * 4, cl = lane & 15;
#pragma unroll
  for (int mi = 0; mi < 2; ++mi)
#pragma unroll
    for (int ni = 0; ni < 4; ++ni)
#pragma unroll
      for (int j = 0; j < 4; ++j) {
        int m = bm + wm + mi * 16 + rg + j;
        int n = bn + wn + ni * 16 + cl;
        float v = fmaxf(acc[mi][ni][j] + bias[n], 0.f);
        Rf[m * 256 + n] = v;
        Rb[m * 256 + n] = (_Float16)v;
      }
}

// ---------------- persistent RNN: 9x r = relu(r@W + b_in + r), then out-proj ----------------
// 256 blocks x 512 threads; block owns 32 rows. W lives in VGPRs (128/wave).
// r: f16 in LDS (swizzled) for cross-wave A-frags; f32 residual in registers.
__global__ __launch_bounds__(512, 2) void rnn_persist_kernel(
    const _Float16* __restrict__ Rb,   // [8192][256] r0 f16
    const float*    __restrict__ Rf,   // [8192][256] r0 f32
    const _Float16* __restrict__ Wt,   // [256][256] n-major, *2^12
    const float*    __restrict__ b_in, // [256]
    const float*    __restrict__ Wo,   // [10][256]
    const float*    __restrict__ bo,   // [10]
    float*          __restrict__ out)  // [8192][10]
{
  // element (row,k) stored at row*256 + (k ^ ((row&7)<<3))  [16B-granular]
  __shared__ __align__(16) _Float16 r_lds[32 * 256];
  int tid = threadIdx.x, lane = tid & 63, wid = tid >> 6;
  int wr = wid >> 2, wc = wid & 3;       // 2M x 4N wave grid; region 16r x 64c
  int bm = blockIdx.x * 32;

  // ---- W fragments -> registers (one-time; plain n-major global) ----
  f16x8 wfr[8][4];
#pragma unroll
  for (int kk = 0; kk < 8; ++kk)
#pragma unroll
    for (int ni = 0; ni < 4; ++ni) {
      int n = wc * 64 + ni * 16 + (lane & 15);
      int kpos = kk * 32 + (lane >> 4) * 8;
      wfr[kk][ni] = *(const f16x8*)(Wt + n * 256 + kpos);
    }

  // ---- bias + f32 residual -> registers ----
  float breg[4];
  float rres[4][4];
  int rrow = wr * 16 + (lane >> 4) * 4;
#pragma unroll
  for (int ni = 0; ni < 4; ++ni) {
    int col = wc * 64 + ni * 16 + (lane & 15);
    breg[ni] = b_in[col];
#pragma unroll
    for (int j = 0; j < 4; ++j)
      rres[ni][j] = Rf[(size_t)(bm + rrow + j) * 256 + col];
  }

  // ---- r0 f16 -> LDS (swizzled): 32 rows x 32 vec8 = 1024 vectors, 512 threads x 2 ----
#pragma unroll
  for (int it = 0; it < 2; ++it) {
    int idx = it * 512 + tid;            // 0..1023
    int row = idx >> 5;                  // 0..31
    int kc = (idx & 31) * 8;             // 0..248
    f16x8 v = *(const f16x8*)(Rb + (size_t)(bm + row) * 256 + kc);
    *(f16x8*)(r_lds + row * 256 + (kc ^ ((row & 7) << 3))) = v;
  }

  int arow = wr * 16 + (lane & 15);
  int aswz = (arow & 7) << 3;
  for (int s = 0; s < 9; ++s) {
    __syncthreads();                     // r_lds writes visible
    f32x4 acc[4];
#pragma unroll
    for (int ni = 0; ni < 4; ++ni) acc[ni] = (f32x4){0.f, 0.f, 0.f, 0.f};
#pragma unroll
    for (int kk = 0; kk < 8; ++kk) {
      int kpos = kk * 32 + (lane >> 4) * 8;
      f16x8 af = *(const f16x8*)(r_lds + arow * 256 + (kpos ^ aswz));
#pragma unroll
      for (int ni = 0; ni < 4; ++ni)
        acc[ni] = __builtin_amdgcn_mfma_f32_16x16x32_f16(af, wfr[kk][ni], acc[ni], 0, 0, 0);
    }
    __syncthreads();                     // all reads done before overwrite
#pragma unroll
    for (int ni = 0; ni < 4; ++ni) {
      int col = wc * 64 + ni * 16 + (lane & 15);
#pragma unroll
      for (int j = 0; j < 4; ++j) {
        float v = fmaxf(fmaf(acc[ni][j], W_UNSCALE, breg[ni] + rres[ni][j]), 0.f);
        rres[ni][j] = v;
        int row = rrow + j;
        r_lds[row * 256 + (col ^ ((row & 7) << 3))] = (_Float16)v;
      }
    }
  }
  __syncthreads();

  // ---- fused out-proj: out[32r][10] = r @ Wo^T + bo ----
  if (tid < 320) {
    int row = tid / 10, o = tid - row * 10;
    int rswz = (row & 7) << 3;
    float accd = 0.f;
    for (int kc = 0; kc < 256; kc += 8) {
      f16x8 rv = *(const f16x8*)(r_lds + row * 256 + (kc ^ rswz));
      const float* wp = Wo + o * 256 + kc;
#pragma unroll
      for (int j = 0; j < 8; ++j) accd = fmaf((float)rv[j], wp[j], accd);
    }
    out[(size_t)(bm + row) * 10 + o] = accd + bo[o];
  }
}

extern "C" void kernel_launch(void* const* d_in, const int* in_sizes, int n_in,
                              void* d_out, int out_size, void* d_ws, size_t ws_size,
                              hipStream_t stream) {
  const float* x      = (const float*)d_in[0];
  const float* conv_w = (const float*)d_in[1];
  const float* conv_b = (const float*)d_in[2];
  const float* W_in   = (const float*)d_in[3];
  const float* b_in   = (const float*)d_in[4];
  const float* W_out  = (const float*)d_in[5];
  const float* b_out  = (const float*)d_in[6];
  const float* W      = (const float*)d_in[7];
  float* out = (float*)d_out;

  char* ws = (char*)d_ws;
  size_t o = 0;
  _Float16* conv_flat = (_Float16*)(ws + o); o += (size_t)8192 * 3136 * 2;
  _Float16* W_in_h    = (_Float16*)(ws + o); o += (size_t)256 * 3136 * 2;
  _Float16* Wt_h      = (_Float16*)(ws + o); o += (size_t)256 * 256 * 2;
  float*    Rf0       = (float*)(ws + o);    o += (size_t)8192 * 256 * 4;
  _Float16* Rb0       = (_Float16*)(ws + o); o += (size_t)8192 * 256 * 2;

  win_cvt_kernel<<<256, 256, 0, stream>>>(W_in, W_in_h);
  wt_cvt_kernel<<<256, 256, 0, stream>>>(W, Wt_h);
  conv_pool_kernel<<<8192, 256, 0, stream>>>(x, conv_w, conv_b, conv_flat);
  gemm1_kernel<<<dim3(128, 2), 256, 0, stream>>>(conv_flat, W_in_h, b_in, Rf0, Rb0);
  rnn_persist_kernel<<<256, 512, 0, stream>>>(Rb0, Rf0, Wt_h, b_in, W_out, b_out, out);
}